// Round 4
// baseline (244.456 us; speedup 1.0000x reference)
//
#include <hip/hip_runtime.h>
#include <math.h>
#include <type_traits>

#define N_NODES 50000
#define N_EDGES 800000
#define DIM 96
#define BCH 12                    // 16-byte chunks per bf16 row (96 shorts)
#define SCAN_BLK 256
#define NBLK ((N_NODES + SCAN_BLK - 1) / SCAN_BLK)    // 196
#define NPB 21                    // nodes per gather block (21*12 = 252 active threads)
#define NBG ((N_NODES + NPB - 1) / NPB)               // 2381 gather blocks
#define CAP 768                   // LDS entry buffer (int2) per tile; multiple of 8
#define R1_ROWS 24
#define R1_BLOCKS ((NBG + R1_ROWS - 1) / R1_ROWS)     // 100
#define SC_PASSES 4
#define SC_WIN ((N_NODES + SC_PASSES - 1) / SC_PASSES)   // 12500 nodes per window
#define ENT_MAX 1200000           // >= sum of padded degrees (800K + 50K*7 worst case)

typedef short v8s __attribute__((ext_vector_type(8)));   // 8 bf16 = 4 VGPRs
typedef float v4f __attribute__((ext_vector_type(4)));   // MFMA accumulator

// ---- bf16 helpers (RNE) ----
__device__ __forceinline__ unsigned short f2bf(float f) {
    unsigned int u = __float_as_uint(f);
    u += 0x7FFFu + ((u >> 16) & 1u);
    return (unsigned short)(u >> 16);
}
__device__ __forceinline__ unsigned int pack2bf(float lo, float hi) {
    return (unsigned int)f2bf(lo) | ((unsigned int)f2bf(hi) << 16);
}
__device__ __forceinline__ float bflo(unsigned int u) { return __uint_as_float(u << 16); }
__device__ __forceinline__ float bfhi(unsigned int u) { return __uint_as_float(u & 0xFFFF0000u); }

__device__ __forceinline__ float fast_tanh(float x) {
    float ax = fabsf(x);
    float t = __expf(-2.0f * ax);
    float r = (1.0f - t) / (1.0f + t);
    return copysignf(r, x);
}

__device__ __forceinline__ void acc8(float* a, uint4 v, float f) {
    a[0] += bflo(v.x) * f; a[1] += bfhi(v.x) * f;
    a[2] += bflo(v.y) * f; a[3] += bfhi(v.y) * f;
    a[4] += bflo(v.z) * f; a[5] += bfhi(v.z) * f;
    a[6] += bflo(v.w) * f; a[7] += bfhi(v.w) * f;
}

union U4S8 { uint4 u; v8s s; };

// ---------------- counting-sort CSR build, 8-padded segments ----------------
// Each node's entry list is padded to a multiple of 8 with {src=0, factor=0}
// (the memset background), so the gather inner loop is pure 8-deep rounds
// with no serial-latency remainder tail.

__global__ void count_deg(const int* __restrict__ dst, int* __restrict__ deg,
                          int* __restrict__ rank) {
    int e = blockIdx.x * blockDim.x + threadIdx.x;
    if (e < N_EDGES) rank[e] = atomicAdd(&deg[dst[e]], 1);
}

__global__ void node_pass(const int* __restrict__ deg, int* __restrict__ degp,
                          float* __restrict__ norm, int* __restrict__ partials) {
    int b = blockIdx.x, t = threadIdx.x;
    int n = b * SCAN_BLK + t;
    int vp = 0;
    if (n < N_NODES) {
        int d = deg[n];
        norm[n] = rsqrtf(fmaxf((float)d, 1.0f));
        vp = (d + 7) & ~7;
        degp[n] = vp;
    }
    int s = vp;
#pragma unroll
    for (int off = 32; off > 0; off >>= 1) s += __shfl_down(s, off, 64);
    __shared__ int ws_[4];
    if ((t & 63) == 0) ws_[t >> 6] = s;
    __syncthreads();
    if (t == 0) partials[b] = ws_[0] + ws_[1] + ws_[2] + ws_[3];
}

__global__ void scan_partials(const int* __restrict__ partials, int* __restrict__ pprefix) {
    __shared__ int sm[SCAN_BLK];
    int t = threadIdx.x;
    int v = (t < NBLK) ? partials[t] : 0;
    sm[t] = v;
    __syncthreads();
    for (int off = 1; off < SCAN_BLK; off <<= 1) {
        int u = (t >= off) ? sm[t - off] : 0;
        __syncthreads();
        sm[t] += u;
        __syncthreads();
    }
    if (t < NBLK) pprefix[t] = sm[t] - v;
}

__global__ void make_offsets(const int* __restrict__ degp, const int* __restrict__ pprefix,
                             int* __restrict__ offs) {
    __shared__ int sm[SCAN_BLK];
    int b = blockIdx.x, t = threadIdx.x;
    int idx = b * SCAN_BLK + t;
    int v = (idx < N_NODES) ? degp[idx] : 0;
    sm[t] = v;
    __syncthreads();
    for (int off = 1; off < SCAN_BLK; off <<= 1) {
        int u = (t >= off) ? sm[t - off] : 0;
        __syncthreads();
        sm[t] += u;
        __syncthreads();
    }
    if (idx < N_NODES) {
        int o = pprefix[b] + sm[t] - v;
        offs[idx] = o;
        if (idx == N_NODES - 1) offs[N_NODES] = o + v;   // total padded count
    }
}

// atomic-free scatter; dst-windowed passes keep the active write region L2-resident
__global__ void scatter_edges(const int* __restrict__ src, const int* __restrict__ dst,
                              const float* __restrict__ factor, const int* __restrict__ rank,
                              const int* __restrict__ offs, int2* __restrict__ entries) {
    int tid0 = blockIdx.x * blockDim.x + threadIdx.x;
    int stride = gridDim.x * blockDim.x;
#pragma unroll 1
    for (int pass = 0; pass < SC_PASSES; ++pass) {
        int lo = pass * SC_WIN;
        int hi = min(lo + SC_WIN, N_NODES);
#pragma unroll 1
        for (int e = tid0; e < N_EDGES; e += stride) {
            int d = dst[e];
            if (d >= lo && d < hi) {
                int pos = offs[d] + rank[e];
                entries[pos] = make_int2(src[e], __float_as_int(factor[e]));
            }
        }
    }
}

// ---------------- W pre-swizzle: B-fragments for mfma_f32_16x16x32_bf16 ----------------
// B[k][n] lane layout: lane holds B[k = (lane>>4)*8 + i][n = lane&15], i=0..7.
// B[k][j] = W[j][k]  ->  lane reads W[jt*16 + (lane&15)][kt*32 + (lane>>4)*8 .. +7]

__global__ void swizzle_W(const float* __restrict__ W, uint4* __restrict__ bsw) {
    int idx = blockIdx.x * blockDim.x + threadIdx.x;
    if (idx >= 18 * 64) return;
    int t = idx >> 6, lane = idx & 63;
    int kt = t / 6, jt = t % 6;
    int quad = lane >> 4, l16 = lane & 15;
    const float4* wp = (const float4*)(W + (size_t)(jt * 16 + l16) * DIM + kt * 32 + quad * 8);
    float4 w0 = wp[0], w1 = wp[1];
    bsw[idx] = make_uint4(pack2bf(w0.x, w0.y), pack2bf(w0.z, w0.w),
                          pack2bf(w1.x, w1.y), pack2bf(w1.z, w1.w));
}

// ---------------- MFMA GEMM:  out[n][j] = bf16((X@W^T + b)[n][j] * norm[n]) ----------------

#define TILE_SH 104   // shorts per LDS tile row

template <typename T>
__global__ __launch_bounds__(256) void gemm_mfma(const T* __restrict__ X,
                                                 const uint4* __restrict__ bsw,
                                                 const float* __restrict__ bias,
                                                 const float* __restrict__ norm,
                                                 unsigned short* __restrict__ out) {
    __shared__ unsigned short tile[4][16 * TILE_SH];   // 13.3 KB
    int tid = threadIdx.x;
    int wave = tid >> 6, lane = tid & 63;
    int quad = lane >> 4, l16 = lane & 15;
    int n0 = blockIdx.x * 64 + wave * 16;
    int rowc = min(n0 + l16, N_NODES - 1);

    // preload all 18 B-fragments (L1-hot: same addresses for every wave/block)
    uint4 bfr[18];
#pragma unroll
    for (int t = 0; t < 18; ++t) bfr[t] = bsw[t * 64 + lane];

    v4f acc[6];
#pragma unroll
    for (int jt = 0; jt < 6; ++jt) acc[jt] = (v4f)(0.0f);

#pragma unroll
    for (int kt = 0; kt < 3; ++kt) {
        U4S8 a;
        if constexpr (std::is_same_v<T, float>) {
            const float4* xp = (const float4*)(X + (size_t)rowc * DIM + kt * 32 + quad * 8);
            float4 x0 = xp[0], x1 = xp[1];
            a.u = make_uint4(pack2bf(x0.x, x0.y), pack2bf(x0.z, x0.w),
                             pack2bf(x1.x, x1.y), pack2bf(x1.z, x1.w));
        } else {
            a.u = *(const uint4*)(X + (size_t)rowc * DIM + kt * 32 + quad * 8);
        }
#pragma unroll
        for (int jt = 0; jt < 6; ++jt) {
            U4S8 bb; bb.u = bfr[kt * 6 + jt];
            acc[jt] = __builtin_amdgcn_mfma_f32_16x16x32_bf16(a.s, bb.s, acc[jt], 0, 0, 0);
        }
    }

    // epilogue: C/D lane layout col=lane&15, row=quad*4+reg
    float nm[4];
#pragma unroll
    for (int r = 0; r < 4; ++r) nm[r] = norm[min(n0 + quad * 4 + r, N_NODES - 1)];
#pragma unroll
    for (int jt = 0; jt < 6; ++jt) {
        float bj = bias[jt * 16 + l16];
#pragma unroll
        for (int r = 0; r < 4; ++r) {
            float v = (acc[jt][r] + bj) * nm[r];
            tile[wave][(quad * 4 + r) * TILE_SH + jt * 16 + l16] = f2bf(v);
        }
    }
    __builtin_amdgcn_s_waitcnt(0);   // drain lgkm before wave-local LDS reads
#pragma unroll
    for (int i = 0; i < 3; ++i) {
        int chunk = lane + 64 * i;        // 0..191 = 16 rows x 12 uint4
        int rr = chunk / 12, cc = chunk - rr * 12;
        int gn = n0 + rr;
        if (gn < N_NODES) {
            uint4 v = *(uint4*)&tile[wave][rr * TILE_SH + cc * 8];
            *(uint4*)(out + (size_t)gn * DIM + cc * 8) = v;
        }
    }
}

// ---------------- gather aggregation: LDS-staged entries, pure 8-deep rounds ----------------

template <bool DO_TANH, bool POOL>
__global__ void gather_agg_bf16(const unsigned short* __restrict__ feat,
                                const int* __restrict__ offs,
                                const int2* __restrict__ entries,
                                unsigned short* __restrict__ out,
                                float* __restrict__ partials) {
    __shared__ int2 ents[CAP];       // 6 KB
    __shared__ float pool[DIM];
    __shared__ int sh_base, sh_cnt;
    int tid = threadIdx.x;
    int n0 = blockIdx.x * NPB;
    int n1 = min(n0 + NPB, N_NODES);
    if (POOL && tid < DIM) pool[tid] = 0.f;
    if (tid == 0) { sh_base = offs[n0]; sh_cnt = offs[n1] - sh_base; }
    __syncthreads();
    int base = sh_base, cnt = sh_cnt;

    int nl = tid / BCH;
    int c  = tid - nl * BCH;
    int n  = n0 + nl;
    bool active = (tid < NPB * BCH) && (n < N_NODES);
    int lb = 0, le = 0;
    if (active) { lb = offs[n] - base; le = offs[n + 1] - base; }

    float a0[8], a1[8];
#pragma unroll
    for (int i = 0; i < 8; ++i) { a0[i] = 0.f; a1[i] = 0.f; }

    for (int tb = 0; tb < cnt; tb += CAP) {
        int tcnt = min(cnt - tb, CAP);
        if (tb) __syncthreads();
        for (int i = tid; i < tcnt; i += 256) ents[i] = entries[base + tb + i];
        __syncthreads();
        // all segment boundaries are multiples of 8 (padded lists, CAP % 8 == 0)
        int s = max(lb - tb, 0), e = min(le - tb, tcnt);
        for (int p = s; p + 7 < e; p += 8) {
            int2 q0 = ents[p + 0], q1 = ents[p + 1], q2 = ents[p + 2], q3 = ents[p + 3];
            int2 q4 = ents[p + 4], q5 = ents[p + 5], q6 = ents[p + 6], q7 = ents[p + 7];
            uint4 v0 = *((const uint4*)(feat + (size_t)q0.x * DIM) + c);
            uint4 v1 = *((const uint4*)(feat + (size_t)q1.x * DIM) + c);
            uint4 v2 = *((const uint4*)(feat + (size_t)q2.x * DIM) + c);
            uint4 v3 = *((const uint4*)(feat + (size_t)q3.x * DIM) + c);
            uint4 v4 = *((const uint4*)(feat + (size_t)q4.x * DIM) + c);
            uint4 v5 = *((const uint4*)(feat + (size_t)q5.x * DIM) + c);
            uint4 v6 = *((const uint4*)(feat + (size_t)q6.x * DIM) + c);
            uint4 v7 = *((const uint4*)(feat + (size_t)q7.x * DIM) + c);
            acc8(a0, v0, __int_as_float(q0.y));
            acc8(a1, v1, __int_as_float(q1.y));
            acc8(a0, v2, __int_as_float(q2.y));
            acc8(a1, v3, __int_as_float(q3.y));
            acc8(a0, v4, __int_as_float(q4.y));
            acc8(a1, v5, __int_as_float(q5.y));
            acc8(a0, v6, __int_as_float(q6.y));
            acc8(a1, v7, __int_as_float(q7.y));
        }
    }

#pragma unroll
    for (int i = 0; i < 8; ++i) a0[i] += a1[i];
    if (DO_TANH || POOL) {
#pragma unroll
        for (int i = 0; i < 8; ++i) a0[i] = fast_tanh(a0[i]);
    }
    if (!POOL) {
        if (active) {
            uint4 o;
            o.x = pack2bf(a0[0], a0[1]);
            o.y = pack2bf(a0[2], a0[3]);
            o.z = pack2bf(a0[4], a0[5]);
            o.w = pack2bf(a0[6], a0[7]);
            ((uint4*)out)[n * BCH + c] = o;
        }
    } else {
        if (active) {
#pragma unroll
            for (int i = 0; i < 8; ++i) atomicAdd(&pool[c * 8 + i], a0[i]);
        }
        __syncthreads();
        if (tid < DIM) partials[(size_t)blockIdx.x * DIM + tid] = pool[tid];
    }
}

// ---------------- two-stage pooled reduce ----------------

__global__ void reduce_stage1(const float* __restrict__ poolpart, float* __restrict__ stage1) {
    __shared__ float pool[DIM];
    int b = blockIdx.x, t = threadIdx.x;
    if (t < DIM) pool[t] = 0.f;
    __syncthreads();
    const int base = b * R1_ROWS * DIM;
    float loc = 0.f;
    int lastc = -1;
    for (int i = t; i < R1_ROWS * DIM; i += 256) {
        int gi = base + i;
        if (gi < NBG * DIM) {
            int col = i % DIM;
            if (col != lastc) {
                if (lastc >= 0) atomicAdd(&pool[lastc], loc);
                lastc = col; loc = 0.f;
            }
            loc += poolpart[gi];
        }
    }
    if (lastc >= 0) atomicAdd(&pool[lastc], loc);
    __syncthreads();
    if (t < DIM) stage1[b * DIM + t] = pool[t];
}

__global__ void reduce_stage2(const float* __restrict__ stage1, float* __restrict__ out) {
    __shared__ float sm[960];
    int t = threadIdx.x;
    int col = t % DIM, slice = t / DIM;
    float s = 0.f;
    for (int k = slice; k < R1_BLOCKS; k += 10) s += stage1[k * DIM + col];
    sm[t] = s;
    __syncthreads();
    if (t < DIM) {
        float tot = 0.f;
#pragma unroll
        for (int i = 0; i < 10; ++i) tot += sm[i * DIM + t];
        out[t] = tanhf(tot * (1.0f / N_NODES));
    }
}

// ---------------- launch ----------------

extern "C" void kernel_launch(void* const* d_in, const int* in_sizes, int n_in,
                              void* d_out, int out_size, void* d_ws, size_t ws_size,
                              hipStream_t stream) {
    const float* inputs = (const float*)d_in[0];
    const float* W1     = (const float*)d_in[1];
    const float* b1     = (const float*)d_in[2];
    const float* W2     = (const float*)d_in[3];
    const float* b2     = (const float*)d_in[4];
    const float* factor = (const float*)d_in[5];
    const int*   src    = (const int*)d_in[6];
    const int*   dst    = (const int*)d_in[7];
    float* out = (float*)d_out;

    char* ws = (char*)d_ws;
    int*            deg      = (int*)(ws + 0);              // 200 KB
    int*            degp     = (int*)(ws + 262144);         // 200 KB
    int*            rank     = (int*)(ws + 524288);         // 3.2 MB
    int*            offs     = (int*)(ws + 3932160);        // 200 KB (+1)
    float*          norm     = (float*)(ws + 4194304);      // 200 KB
    int*            partials = (int*)(ws + 4456448);        // 1 KB
    int*            pprefix  = (int*)(ws + 4458496);        // 1 KB
    int2*           entries  = (int2*)(ws + 4718592);       // 9.6 MB (padded)
    unsigned short* bufA     = (unsigned short*)(ws + 14680064);  // 9.6 MB bf16 feat
    unsigned short* bufB     = (unsigned short*)(ws + 24379392);  // 9.6 MB bf16 feat
    float*          poolpart = (float*)(ws + 34078720);     // 914 KB (NBG x 96)
    float*          stage1   = (float*)(ws + 35127296);     // 38.4 KB
    uint4*          bsw1     = (uint4*)(ws + 35184640);     // 18 KB W1 fragments
    uint4*          bsw2     = (uint4*)(ws + 35205632);     // 18 KB W2 fragments

    // W fragment pre-swizzle (independent of CSR build)
    swizzle_W<<<5, 256, 0, stream>>>(W1, bsw1);
    swizzle_W<<<5, 256, 0, stream>>>(W2, bsw2);

    // counting-sort CSR build with 8-padded segments; pad slots stay {0, 0.0f}
    hipMemsetAsync(deg, 0, N_NODES * sizeof(int), stream);
    hipMemsetAsync(entries, 0, (size_t)ENT_MAX * sizeof(int2), stream);
    count_deg<<<(N_EDGES + 255) / 256, 256, 0, stream>>>(dst, deg, rank);
    node_pass<<<NBLK, SCAN_BLK, 0, stream>>>(deg, degp, norm, partials);
    scan_partials<<<1, SCAN_BLK, 0, stream>>>(partials, pprefix);
    make_offsets<<<NBLK, SCAN_BLK, 0, stream>>>(degp, pprefix, offs);
    scatter_edges<<<2048, 256, 0, stream>>>(src, dst, factor, rank, offs, entries);

    const int GEMM_BLOCKS = (N_NODES + 63) / 64;   // 782

    // layer 1
    gemm_mfma<float><<<GEMM_BLOCKS, 256, 0, stream>>>(inputs, bsw1, b1, norm, bufA);
    gather_agg_bf16<true, false><<<NBG, 256, 0, stream>>>(bufA, offs, entries, bufB, nullptr);

    // layer 2 (gather fuses tanh + column pooling, no feature write)
    gemm_mfma<unsigned short><<<GEMM_BLOCKS, 256, 0, stream>>>(bufB, bsw2, b2, norm, bufA);
    gather_agg_bf16<false, true><<<NBG, 256, 0, stream>>>(bufA, offs, entries, nullptr, poolpart);

    // two-stage pooled reduce -> out
    reduce_stage1<<<R1_BLOCKS, 256, 0, stream>>>(poolpart, stage1);
    reduce_stage2<<<1, 960, 0, stream>>>(stage1, out);
}

// Round 5
// 232.642 us; speedup vs baseline: 1.0508x; 1.0508x over previous
//
#include <hip/hip_runtime.h>
#include <math.h>
#include <type_traits>

#define N_NODES 50000
#define N_EDGES 800000
#define DIM 96
#define BCH 12                    // 8-byte fp8 chunks per 96B row
#define SCAN_BLK 256
#define NBLK ((N_NODES + SCAN_BLK - 1) / SCAN_BLK)    // 196
#define NPB 21                    // nodes per gather block (21*12 = 252 active threads)
#define NBG ((N_NODES + NPB - 1) / NPB)               // 2381 gather blocks
#define CAP 768                   // LDS entry buffer (int2) per tile
#define R1_ROWS 24
#define R1_BLOCKS ((NBG + R1_ROWS - 1) / R1_ROWS)     // 100
#define SC_PASSES 4
#define SC_WIN ((N_NODES + SC_PASSES - 1) / SC_PASSES)   // 12500 nodes per window
#define F8_SCALE 16.0f
#define F8_INV   0.0625f

typedef short v8s __attribute__((ext_vector_type(8)));   // 8 bf16 = 4 VGPRs
typedef float v4f __attribute__((ext_vector_type(4)));   // MFMA accumulator
typedef float v2f __attribute__((ext_vector_type(2)));

// ---- bf16 helpers (RNE) ----
__device__ __forceinline__ unsigned short f2bf(float f) {
    unsigned int u = __float_as_uint(f);
    u += 0x7FFFu + ((u >> 16) & 1u);
    return (unsigned short)(u >> 16);
}
__device__ __forceinline__ unsigned int pack2bf(float lo, float hi) {
    return (unsigned int)f2bf(lo) | ((unsigned int)f2bf(hi) << 16);
}

__device__ __forceinline__ float fast_tanh(float x) {
    float ax = fabsf(x);
    float t = __expf(-2.0f * ax);
    float r = (1.0f - t) / (1.0f + t);
    return copysignf(r, x);
}

// fp8 e4m3 (OCP on gfx950): 8 fp8 in a uint2 -> 8 f32 accumulate
__device__ __forceinline__ void accf8(float* a, uint2 v, float f) {
    v2f p0 = __builtin_amdgcn_cvt_pk_f32_fp8(v.x, false);
    v2f p1 = __builtin_amdgcn_cvt_pk_f32_fp8(v.x, true);
    v2f p2 = __builtin_amdgcn_cvt_pk_f32_fp8(v.y, false);
    v2f p3 = __builtin_amdgcn_cvt_pk_f32_fp8(v.y, true);
    a[0] += p0.x * f; a[1] += p0.y * f;
    a[2] += p1.x * f; a[3] += p1.y * f;
    a[4] += p2.x * f; a[5] += p2.y * f;
    a[6] += p3.x * f; a[7] += p3.y * f;
}

union U4S8 { uint4 u; v8s s; };

// ---------------- counting-sort CSR build (rank captured in count pass) ----------------

__global__ void count_deg(const int* __restrict__ dst, int* __restrict__ deg,
                          int* __restrict__ rank) {
    int e = blockIdx.x * blockDim.x + threadIdx.x;
    if (e < N_EDGES) rank[e] = atomicAdd(&deg[dst[e]], 1);
}

__global__ void deg_partials(const int* __restrict__ deg, float* __restrict__ norm,
                             int* __restrict__ partials) {
    int b = blockIdx.x, t = threadIdx.x;
    int n = b * SCAN_BLK + t;
    int v = 0;
    if (n < N_NODES) {
        v = deg[n];
        norm[n] = rsqrtf(fmaxf((float)v, 1.0f));
    }
    int s = v;
#pragma unroll
    for (int off = 32; off > 0; off >>= 1) s += __shfl_down(s, off, 64);
    __shared__ int ws_[4];
    if ((t & 63) == 0) ws_[t >> 6] = s;
    __syncthreads();
    if (t == 0) partials[b] = ws_[0] + ws_[1] + ws_[2] + ws_[3];
}

__global__ void scan_partials(const int* __restrict__ partials, int* __restrict__ pprefix) {
    __shared__ int sm[SCAN_BLK];
    int t = threadIdx.x;
    int v = (t < NBLK) ? partials[t] : 0;
    sm[t] = v;
    __syncthreads();
    for (int off = 1; off < SCAN_BLK; off <<= 1) {
        int u = (t >= off) ? sm[t - off] : 0;
        __syncthreads();
        sm[t] += u;
        __syncthreads();
    }
    if (t < NBLK) pprefix[t] = sm[t] - v;
}

__global__ void make_offsets(const int* __restrict__ deg, const int* __restrict__ pprefix,
                             int* __restrict__ offs) {
    __shared__ int sm[SCAN_BLK];
    int b = blockIdx.x, t = threadIdx.x;
    int idx = b * SCAN_BLK + t;
    int v = (idx < N_NODES) ? deg[idx] : 0;
    sm[t] = v;
    __syncthreads();
    for (int off = 1; off < SCAN_BLK; off <<= 1) {
        int u = (t >= off) ? sm[t - off] : 0;
        __syncthreads();
        sm[t] += u;
        __syncthreads();
    }
    if (idx < N_NODES) offs[idx] = pprefix[b] + sm[t] - v;
    if (b == 0 && t == 0) offs[N_NODES] = N_EDGES;
}

// atomic-free scatter; dst-windowed passes keep the active write region L2-resident
__global__ void scatter_edges(const int* __restrict__ src, const int* __restrict__ dst,
                              const float* __restrict__ factor, const int* __restrict__ rank,
                              const int* __restrict__ offs, int2* __restrict__ entries) {
    int tid0 = blockIdx.x * blockDim.x + threadIdx.x;
    int stride = gridDim.x * blockDim.x;
#pragma unroll 1
    for (int pass = 0; pass < SC_PASSES; ++pass) {
        int lo = pass * SC_WIN;
        int hi = min(lo + SC_WIN, N_NODES);
#pragma unroll 1
        for (int e = tid0; e < N_EDGES; e += stride) {
            int d = dst[e];
            if (d >= lo && d < hi) {
                int pos = offs[d] + rank[e];
                entries[pos] = make_int2(src[e], __float_as_int(factor[e]));
            }
        }
    }
}

// ---------------- W pre-swizzle: k-contiguous fragments for mfma_f32_16x16x32_bf16 ----
// Lane holds W[jt*16 + (lane&15)][kt*32 + (lane>>4)*8 .. +7] packed to 8 bf16.
// Used as the A operand (A[row=j][k]) of D = W x X^T.

__global__ void swizzle_W(const float* __restrict__ W, uint4* __restrict__ bsw) {
    int idx = blockIdx.x * blockDim.x + threadIdx.x;
    if (idx >= 18 * 64) return;
    int t = idx >> 6, lane = idx & 63;
    int kt = t / 6, jt = t % 6;
    int quad = lane >> 4, l16 = lane & 15;
    const float4* wp = (const float4*)(W + (size_t)(jt * 16 + l16) * DIM + kt * 32 + quad * 8);
    float4 w0 = wp[0], w1 = wp[1];
    bsw[idx] = make_uint4(pack2bf(w0.x, w0.y), pack2bf(w0.z, w0.w),
                          pack2bf(w1.x, w1.y), pack2bf(w1.z, w1.w));
}

// ---------------- MFMA GEMM (operand-swapped):  D = W x X^T ----------------
// D col = node (lane&15), D row = feature dim j = jt*16 + quad*4 + r.
// Each lane packs its 4 consecutive j-values to 4 fp8 -> one dword store.
// out[n][j] = fp8( (X@W^T + b)[n][j] * norm[n] * 16 )

template <typename T>
__global__ __launch_bounds__(256) void gemm_mfma(const T* __restrict__ X,
                                                 const uint4* __restrict__ bsw,
                                                 const float* __restrict__ bias,
                                                 const float* __restrict__ norm,
                                                 unsigned char* __restrict__ out) {
    int tid = threadIdx.x;
    int wave = tid >> 6, lane = tid & 63;
    int quad = lane >> 4, l16 = lane & 15;
    int n0 = blockIdx.x * 64 + wave * 16;
    int node = n0 + l16;
    int rowc = min(node, N_NODES - 1);

    // preload all 18 W-fragments (L1-hot: same addresses for every wave/block)
    uint4 bfr[18];
#pragma unroll
    for (int t = 0; t < 18; ++t) bfr[t] = bsw[t * 64 + lane];

    v4f acc[6];
#pragma unroll
    for (int jt = 0; jt < 6; ++jt) acc[jt] = (v4f)(0.0f);

#pragma unroll
    for (int kt = 0; kt < 3; ++kt) {
        U4S8 x;
        if constexpr (std::is_same_v<T, float>) {
            const float4* xp = (const float4*)(X + (size_t)rowc * DIM + kt * 32 + quad * 8);
            float4 x0 = xp[0], x1 = xp[1];
            x.u = make_uint4(pack2bf(x0.x, x0.y), pack2bf(x0.z, x0.w),
                             pack2bf(x1.x, x1.y), pack2bf(x1.z, x1.w));
        } else {
            x.u = *(const uint4*)(X + (size_t)rowc * DIM + kt * 32 + quad * 8);
        }
#pragma unroll
        for (int jt = 0; jt < 6; ++jt) {
            U4S8 w; w.u = bfr[kt * 6 + jt];
            // A = W fragment, B = X fragment  ->  D[j][node]
            acc[jt] = __builtin_amdgcn_mfma_f32_16x16x32_bf16(w.s, x.s, acc[jt], 0, 0, 0);
        }
    }

    if (node < N_NODES) {
        float nm = norm[node] * F8_SCALE;
#pragma unroll
        for (int jt = 0; jt < 6; ++jt) {
            float4 bj = *(const float4*)(bias + jt * 16 + quad * 4);
            float v0 = (acc[jt][0] + bj.x) * nm;
            float v1 = (acc[jt][1] + bj.y) * nm;
            float v2 = (acc[jt][2] + bj.z) * nm;
            float v3 = (acc[jt][3] + bj.w) * nm;
            unsigned int w = (unsigned int)__builtin_amdgcn_cvt_pk_fp8_f32(v0, v1, 0, false);
            w = (unsigned int)__builtin_amdgcn_cvt_pk_fp8_f32(v2, v3, (int)w, true);
            *(unsigned int*)(out + (size_t)node * DIM + jt * 16 + quad * 4) = w;
        }
    }
}

// ---------------- gather aggregation: fp8 feat rows (96B), LDS-staged entries ----------

template <bool POOL>
__global__ void gather_agg_f8(const unsigned char* __restrict__ feat,
                              const int* __restrict__ offs,
                              const int2* __restrict__ entries,
                              unsigned short* __restrict__ out,
                              float* __restrict__ partials) {
    __shared__ int2 ents[CAP];       // 6 KB
    __shared__ float pool[DIM];
    __shared__ int sh_base, sh_cnt;
    int tid = threadIdx.x;
    int n0 = blockIdx.x * NPB;
    int n1 = min(n0 + NPB, N_NODES);
    if (POOL && tid < DIM) pool[tid] = 0.f;
    if (tid == 0) { sh_base = offs[n0]; sh_cnt = offs[n1] - sh_base; }
    __syncthreads();
    int base = sh_base, cnt = sh_cnt;

    int nl = tid / BCH;
    int c  = tid - nl * BCH;
    int n  = n0 + nl;
    bool active = (tid < NPB * BCH) && (n < N_NODES);
    int lb = 0, le = 0;
    if (active) { lb = offs[n] - base; le = offs[n + 1] - base; }

    float a0[8], a1[8];
#pragma unroll
    for (int i = 0; i < 8; ++i) { a0[i] = 0.f; a1[i] = 0.f; }

    for (int tb = 0; tb < cnt; tb += CAP) {
        int tcnt = min(cnt - tb, CAP);
        if (tb) __syncthreads();
        for (int i = tid; i < tcnt; i += 256) ents[i] = entries[base + tb + i];
        __syncthreads();
        int s = max(lb - tb, 0), e = min(le - tb, tcnt);
        int p = s;
        // 8-deep: 8 independent 8B gathers in flight
        for (; p + 7 < e; p += 8) {
            int2 q0 = ents[p + 0], q1 = ents[p + 1], q2 = ents[p + 2], q3 = ents[p + 3];
            int2 q4 = ents[p + 4], q5 = ents[p + 5], q6 = ents[p + 6], q7 = ents[p + 7];
            uint2 v0 = *((const uint2*)(feat + (size_t)q0.x * DIM) + c);
            uint2 v1 = *((const uint2*)(feat + (size_t)q1.x * DIM) + c);
            uint2 v2 = *((const uint2*)(feat + (size_t)q2.x * DIM) + c);
            uint2 v3 = *((const uint2*)(feat + (size_t)q3.x * DIM) + c);
            uint2 v4 = *((const uint2*)(feat + (size_t)q4.x * DIM) + c);
            uint2 v5 = *((const uint2*)(feat + (size_t)q5.x * DIM) + c);
            uint2 v6 = *((const uint2*)(feat + (size_t)q6.x * DIM) + c);
            uint2 v7 = *((const uint2*)(feat + (size_t)q7.x * DIM) + c);
            accf8(a0, v0, __int_as_float(q0.y));
            accf8(a1, v1, __int_as_float(q1.y));
            accf8(a0, v2, __int_as_float(q2.y));
            accf8(a1, v3, __int_as_float(q3.y));
            accf8(a0, v4, __int_as_float(q4.y));
            accf8(a1, v5, __int_as_float(q5.y));
            accf8(a0, v6, __int_as_float(q6.y));
            accf8(a1, v7, __int_as_float(q7.y));
        }
        for (; p + 3 < e; p += 4) {
            int2 q0 = ents[p], q1 = ents[p + 1], q2 = ents[p + 2], q3 = ents[p + 3];
            uint2 v0 = *((const uint2*)(feat + (size_t)q0.x * DIM) + c);
            uint2 v1 = *((const uint2*)(feat + (size_t)q1.x * DIM) + c);
            uint2 v2 = *((const uint2*)(feat + (size_t)q2.x * DIM) + c);
            uint2 v3 = *((const uint2*)(feat + (size_t)q3.x * DIM) + c);
            accf8(a0, v0, __int_as_float(q0.y));
            accf8(a1, v1, __int_as_float(q1.y));
            accf8(a0, v2, __int_as_float(q2.y));
            accf8(a1, v3, __int_as_float(q3.y));
        }
        for (; p < e; ++p) {
            int2 q0 = ents[p];
            uint2 v0 = *((const uint2*)(feat + (size_t)q0.x * DIM) + c);
            accf8(a0, v0, __int_as_float(q0.y));
        }
    }

#pragma unroll
    for (int i = 0; i < 8; ++i) a0[i] = fast_tanh((a0[i] + a1[i]) * F8_INV);
    if (!POOL) {
        if (active) {
            uint4 o;
            o.x = pack2bf(a0[0], a0[1]);
            o.y = pack2bf(a0[2], a0[3]);
            o.z = pack2bf(a0[4], a0[5]);
            o.w = pack2bf(a0[6], a0[7]);
            ((uint4*)out)[n * BCH + c] = o;
        }
    } else {
        if (active) {
#pragma unroll
            for (int i = 0; i < 8; ++i) atomicAdd(&pool[c * 8 + i], a0[i]);
        }
        __syncthreads();
        if (tid < DIM) partials[(size_t)blockIdx.x * DIM + tid] = pool[tid];
    }
}

// ---------------- two-stage pooled reduce ----------------

__global__ void reduce_stage1(const float* __restrict__ poolpart, float* __restrict__ stage1) {
    __shared__ float pool[DIM];
    int b = blockIdx.x, t = threadIdx.x;
    if (t < DIM) pool[t] = 0.f;
    __syncthreads();
    const int base = b * R1_ROWS * DIM;
    float loc = 0.f;
    int lastc = -1;
    for (int i = t; i < R1_ROWS * DIM; i += 256) {
        int gi = base + i;
        if (gi < NBG * DIM) {
            int col = i % DIM;
            if (col != lastc) {
                if (lastc >= 0) atomicAdd(&pool[lastc], loc);
                lastc = col; loc = 0.f;
            }
            loc += poolpart[gi];
        }
    }
    if (lastc >= 0) atomicAdd(&pool[lastc], loc);
    __syncthreads();
    if (t < DIM) stage1[b * DIM + t] = pool[t];
}

__global__ void reduce_stage2(const float* __restrict__ stage1, float* __restrict__ out) {
    __shared__ float sm[960];
    int t = threadIdx.x;
    int col = t % DIM, slice = t / DIM;
    float s = 0.f;
    for (int k = slice; k < R1_BLOCKS; k += 10) s += stage1[k * DIM + col];
    sm[t] = s;
    __syncthreads();
    if (t < DIM) {
        float tot = 0.f;
#pragma unroll
        for (int i = 0; i < 10; ++i) tot += sm[i * DIM + t];
        out[t] = tanhf(tot * (1.0f / N_NODES));
    }
}

// ---------------- launch ----------------

extern "C" void kernel_launch(void* const* d_in, const int* in_sizes, int n_in,
                              void* d_out, int out_size, void* d_ws, size_t ws_size,
                              hipStream_t stream) {
    const float* inputs = (const float*)d_in[0];
    const float* W1     = (const float*)d_in[1];
    const float* b1     = (const float*)d_in[2];
    const float* W2     = (const float*)d_in[3];
    const float* b2     = (const float*)d_in[4];
    const float* factor = (const float*)d_in[5];
    const int*   src    = (const int*)d_in[6];
    const int*   dst    = (const int*)d_in[7];
    float* out = (float*)d_out;

    char* ws = (char*)d_ws;
    int*            deg      = (int*)(ws + 0);              // 200 KB
    int*            rank     = (int*)(ws + 262144);         // 3.2 MB
    int*            offs     = (int*)(ws + 3932160);        // 200 KB (+1)
    float*          norm     = (float*)(ws + 4194304);      // 200 KB
    int*            partials = (int*)(ws + 4456448);        // 1 KB
    int*            pprefix  = (int*)(ws + 4458496);        // 1 KB
    int2*           entries  = (int2*)(ws + 4718592);       // 6.4 MB
    unsigned char*  bufA     = (unsigned char*)(ws + 11534336);   // 4.8 MB fp8 feat
    unsigned short* bufB     = (unsigned short*)(ws + 21364736);  // 9.6 MB bf16 h1
    float*          poolpart = (float*)(ws + 31195136);     // 914 KB (NBG x 96)
    float*          stage1   = (float*)(ws + 32145536);     // 38.4 KB
    uint4*          bsw1     = (uint4*)(ws + 33554432);     // 18 KB W1 fragments
    uint4*          bsw2     = (uint4*)(ws + 33574912);     // 18 KB W2 fragments

    // W fragment pre-swizzle (independent of CSR build)
    swizzle_W<<<5, 256, 0, stream>>>(W1, bsw1);
    swizzle_W<<<5, 256, 0, stream>>>(W2, bsw2);

    // counting-sort CSR build (rank captured during count; scatter is atomic-free)
    hipMemsetAsync(deg, 0, N_NODES * sizeof(int), stream);
    count_deg<<<(N_EDGES + 255) / 256, 256, 0, stream>>>(dst, deg, rank);
    deg_partials<<<NBLK, SCAN_BLK, 0, stream>>>(deg, norm, partials);
    scan_partials<<<1, SCAN_BLK, 0, stream>>>(partials, pprefix);
    make_offsets<<<NBLK, SCAN_BLK, 0, stream>>>(deg, pprefix, offs);
    scatter_edges<<<2048, 256, 0, stream>>>(src, dst, factor, rank, offs, entries);

    const int GEMM_BLOCKS = (N_NODES + 63) / 64;   // 782

    // layer 1: feat1 (fp8) -> gather (+tanh) -> h1 (bf16)
    gemm_mfma<float><<<GEMM_BLOCKS, 256, 0, stream>>>(inputs, bsw1, b1, norm, bufA);
    gather_agg_f8<false><<<NBG, 256, 0, stream>>>(bufA, offs, entries, bufB, nullptr);

    // layer 2: feat2 (fp8) -> gather (+tanh + pool)
    gemm_mfma<unsigned short><<<GEMM_BLOCKS, 256, 0, stream>>>(bufB, bsw2, b2, norm, bufA);
    gather_agg_f8<true><<<NBG, 256, 0, stream>>>(bufA, offs, entries, nullptr, poolpart);

    // two-stage pooled reduce -> out
    reduce_stage1<<<R1_BLOCKS, 256, 0, stream>>>(poolpart, stage1);
    reduce_stage2<<<1, 960, 0, stream>>>(stage1, out);
}